// Round 1
// baseline (385.413 us; speedup 1.0000x reference)
//
#include <hip/hip_runtime.h>
#include <math.h>

#define S_LEN 2048
#define B_SZ  2
#define H_DIM 512
#define WIN   128
#define PAD   64
#define SP    (S_LEN + WIN)   /* 2176 padded seq length */
#define SCALE 0.044194173824159216f  /* 1/sqrt(512) */

// ---------------- RoPE tables -------------------------------------------
// reference: inv_freq_i = 10000^(-2i/512), i in 0..255 ; f_i(t) = t*inv_freq_i
// emb = [sin(f_0..255), cos(f_0..255)]
// emb_sin[j] = j<128 ? sin(f_{2j})   : cos(f_{2(j-128)})
// emb_cos[j] = j<128 ? sin(f_{2j+1}) : cos(f_{2(j-128)+1})
__global__ void rope_tables_k(float* __restrict__ sinT, float* __restrict__ cosT) {
  int idx = blockIdx.x * blockDim.x + threadIdx.x;
  if (idx >= S_LEN * 256) return;
  int s = idx >> 8, j = idx & 255;
  int jj = j & 127;
  double t  = (double)s;
  double fA = t * pow(10000.0, -(double)jj / 128.0);          // freq index 2*jj
  double fB = t * pow(10000.0, -(double)(2 * jj + 1) / 256.0); // freq index 2*jj+1
  if (j < 128) { sinT[idx] = (float)sin(fA); cosT[idx] = (float)sin(fB); }
  else         { sinT[idx] = (float)cos(fA); cosT[idx] = (float)cos(fB); }
}

// ---------------- zero the pad rows of pK / pV --------------------------
__global__ void zero_pads_k(float* __restrict__ pK, float* __restrict__ pV) {
  int idx = blockIdx.x * blockDim.x + threadIdx.x;
  const int n = B_SZ * 2 * PAD * H_DIM; // 131072 per buffer
  if (idx >= 2 * n) return;
  float* p = (idx < n) ? pK : pV;
  int r    = idx & (n - 1);
  int b    = r / (2 * PAD * H_DIM);
  int rem  = r % (2 * PAD * H_DIM);
  int side = rem / (PAD * H_DIM);
  int rr   = rem % (PAD * H_DIM);
  int row  = (side == 0) ? (rr / H_DIM) : (PAD + S_LEN + rr / H_DIM);
  int h    = rr % H_DIM;
  p[((size_t)b * SP + row) * H_DIM + h] = 0.f;
}

// ---------------- f32 GEMM: C[M][512] = A[M][512] @ W[512][512]^T + bias -
// W row-major [n][k] (so A@W.T is K-contiguous in both operands).
// PAD_OUT remaps row r -> r + 64 + 128*(r>>11) (write into padded pV interior).
template<bool PAD_OUT>
__global__ __launch_bounds__(256) void gemm_bt_k(const float* __restrict__ A,
    const float* __restrict__ Wm, const float* __restrict__ bias,
    float* __restrict__ C) {
  __shared__ float As[64][17];
  __shared__ float Bs[64][17];
  int tid = threadIdx.x;
  int tx = tid & 15, ty = tid >> 4;
  int row0 = blockIdx.x * 64, col0 = blockIdx.y * 64;
  float acc[4][4] = {};
  for (int k0 = 0; k0 < H_DIM; k0 += 16) {
#pragma unroll
    for (int l = 0; l < 4; l++) {
      int e = tid + l * 256;
      int m = e >> 4, kk = e & 15;
      As[m][kk] = A [(size_t)(row0 + m) * H_DIM + k0 + kk];
      Bs[m][kk] = Wm[(size_t)(col0 + m) * H_DIM + k0 + kk];
    }
    __syncthreads();
#pragma unroll
    for (int kk = 0; kk < 16; kk++) {
      float a[4], b[4];
#pragma unroll
      for (int i = 0; i < 4; i++) a[i] = As[ty * 4 + i][kk];
#pragma unroll
      for (int j = 0; j < 4; j++) b[j] = Bs[tx * 4 + j][kk];
#pragma unroll
      for (int i = 0; i < 4; i++)
#pragma unroll
        for (int j = 0; j < 4; j++) acc[i][j] += a[i] * b[j];
    }
    __syncthreads();
  }
#pragma unroll
  for (int i = 0; i < 4; i++) {
    int r = row0 + ty * 4 + i;
    int orow = PAD_OUT ? (r + PAD + WIN * (r >> 11)) : r;
#pragma unroll
    for (int j = 0; j < 4; j++) {
      int c = col0 + tx * 4 + j;
      C[(size_t)orow * H_DIM + c] = acc[i][j] + bias[c];
    }
  }
}

// ---------------- RoPE apply --------------------------------------------
// out[j]     = v[2j]*emb_cos[j] - v[2j+1]*emb_sin[j]
// out[256+j] = v[2j]*emb_sin[j] + v[2j+1]*emb_cos[j]
template<bool PAD_OUT>
__global__ void rope_k(const float* __restrict__ in, float* __restrict__ out,
                       const float* __restrict__ sinT, const float* __restrict__ cosT) {
  int idx = blockIdx.x * blockDim.x + threadIdx.x; // B*S*256
  if (idx >= B_SZ * S_LEN * 256) return;
  int row = idx >> 8, j = idx & 255;
  int s = row & (S_LEN - 1);
  const float2 v = ((const float2*)(in + (size_t)row * H_DIM))[j];
  float es = sinT[s * 256 + j], ec = cosT[s * 256 + j];
  int orow = PAD_OUT ? (row + PAD + WIN * (row >> 11)) : row;
  out[(size_t)orow * H_DIM + j]       = v.x * ec - v.y * es;
  out[(size_t)orow * H_DIM + 256 + j] = v.x * es + v.y * ec;
}

// ---------------- windowed attention, one block per query ---------------
__global__ __launch_bounds__(256) void attn_k(const float* __restrict__ rQ,
    const float* __restrict__ pK, const float* __restrict__ pV,
    float* __restrict__ out) {
  int bq = blockIdx.x;                // b*S + s
  int b = bq >> 11, s = bq & (S_LEN - 1);
  int tid = threadIdx.x;
  __shared__ __align__(16) float qs[H_DIM];
  __shared__ float sc2[2][WIN];
  __shared__ float sc[WIN];
  __shared__ float redm[4], reds[4];
  const float* qrow = rQ + (size_t)bq * H_DIM;
  qs[tid]       = qrow[tid];
  qs[tid + 256] = qrow[tid + 256];
  __syncthreads();
  // scores: 2 threads per window position (each sums 256 of 512 dims)
  int w = tid & (WIN - 1), half = tid >> 7;
  const float4* k4 = (const float4*)(pK + ((size_t)(b * SP + s + w)) * H_DIM + half * 256);
  const float4* q4 = (const float4*)(qs + half * 256);
  float p = 0.f;
#pragma unroll 8
  for (int i = 0; i < 64; i++) {
    float4 kv = k4[i], qv = q4[i];
    p += qv.x * kv.x + qv.y * kv.y + qv.z * kv.z + qv.w * kv.w;
  }
  sc2[half][w] = p;
  __syncthreads();
  float sval = -1e30f;
  if (tid < WIN) sval = (sc2[0][tid] + sc2[1][tid]) * SCALE;
  // block max (padded-zero K rows give score 0 and DO join the softmax)
  float m = sval;
#pragma unroll
  for (int off = 32; off; off >>= 1) m = fmaxf(m, __shfl_xor(m, off));
  if ((tid & 63) == 0) redm[tid >> 6] = m;
  __syncthreads();
  m = fmaxf(fmaxf(redm[0], redm[1]), fmaxf(redm[2], redm[3]));
  float e = (tid < WIN) ? expf(sval - m) : 0.f;
  float ssum = e;
#pragma unroll
  for (int off = 32; off; off >>= 1) ssum += __shfl_xor(ssum, off);
  if ((tid & 63) == 0) reds[tid >> 6] = ssum;
  __syncthreads();
  float tot = reds[0] + reds[1] + reds[2] + reds[3];
  if (tid < WIN) sc[tid] = e / tot;
  __syncthreads();
  // PV: each thread owns 2 output dims
  const float* vbase = pV + (size_t)(b * SP + s) * H_DIM;
  float a0 = 0.f, a1 = 0.f;
  for (int ww = 0; ww < WIN; ww++) {
    float wt = sc[ww];
    a0 += wt * vbase[(size_t)ww * H_DIM + tid];
    a1 += wt * vbase[(size_t)ww * H_DIM + 256 + tid];
  }
  out[(size_t)bq * H_DIM + tid]       = a0;
  out[(size_t)bq * H_DIM + 256 + tid] = a1;
}

// ---------------- launch -------------------------------------------------
extern "C" void kernel_launch(void* const* d_in, const int* in_sizes, int n_in,
                              void* d_out, int out_size, void* d_ws, size_t ws_size,
                              hipStream_t stream) {
  const float* x  = (const float*)d_in[0];
  const float* Wq = (const float*)d_in[1];
  const float* bq = (const float*)d_in[2];
  const float* Wk = (const float*)d_in[3];
  const float* bk = (const float*)d_in[4];
  const float* Wv = (const float*)d_in[5];
  const float* bv = (const float*)d_in[6];
  const float* Wo = (const float*)d_in[7];
  const float* bo = (const float*)d_in[8];
  float* out = (float*)d_out;

  const size_t NQ = (size_t)B_SZ * S_LEN * H_DIM;  // 2,097,152
  const size_t NP = (size_t)B_SZ * SP * H_DIM;     // 2,228,224
  float* ws   = (float*)d_ws;
  float* Q    = ws;            // NQ   (pre-rope Q)
  float* Kt   = Q + NQ;        // NQ   (pre-rope K)
  float* rQ   = Kt + NQ;       // NQ   (rope'd Q)
  float* attn = rQ + NQ;       // NQ   (attention output)
  float* pK   = attn + NQ;     // NP   (padded rope'd K)
  float* pV   = pK + NP;       // NP   (padded V)
  float* sinT = pV + NP;       // S*256
  float* cosT = sinT + (size_t)S_LEN * 256;
  // total ws: ~55.6 MB

  rope_tables_k<<<(S_LEN * 256 + 255) / 256, 256, 0, stream>>>(sinT, cosT);
  zero_pads_k<<<(2 * B_SZ * 2 * PAD * H_DIM + 255) / 256, 256, 0, stream>>>(pK, pV);

  dim3 g(B_SZ * S_LEN / 64, H_DIM / 64);
  gemm_bt_k<false><<<g, 256, 0, stream>>>(x, Wq, bq, Q);
  gemm_bt_k<false><<<g, 256, 0, stream>>>(x, Wk, bk, Kt);
  gemm_bt_k<true ><<<g, 256, 0, stream>>>(x, Wv, bv, pV);

  int nrope = B_SZ * S_LEN * 256;
  rope_k<false><<<(nrope + 255) / 256, 256, 0, stream>>>(Q,  rQ, sinT, cosT);
  rope_k<true ><<<(nrope + 255) / 256, 256, 0, stream>>>(Kt, pK, sinT, cosT);

  attn_k<<<B_SZ * S_LEN, 256, 0, stream>>>(rQ, pK, pV, attn);

  gemm_bt_k<false><<<g, 256, 0, stream>>>(attn, Wo, bo, out);
}

// Round 2
// 232.828 us; speedup vs baseline: 1.6554x; 1.6554x over previous
//
#include <hip/hip_runtime.h>
#include <math.h>

#define S_LEN 2048
#define B_SZ  2
#define H_DIM 512
#define WIN   128
#define PAD   64
#define SP    (S_LEN + WIN)   /* 2176 padded seq length */
#define SCALE 0.044194173824159216f  /* 1/sqrt(512) */

typedef __bf16 bf16;
typedef __attribute__((ext_vector_type(8))) __bf16 bf16x8;
typedef __attribute__((ext_vector_type(4))) __bf16 bf16x4;
typedef __attribute__((ext_vector_type(4))) float f32x4;

// ---------------- RoPE tables (f64 on device; verified round 1) ---------
__global__ void rope_tables_k(float* __restrict__ sinT, float* __restrict__ cosT) {
  int idx = blockIdx.x * blockDim.x + threadIdx.x;
  if (idx >= S_LEN * 256) return;
  int s = idx >> 8, j = idx & 255;
  int jj = j & 127;
  double t  = (double)s;
  double fA = t * pow(10000.0, -(double)jj / 128.0);
  double fB = t * pow(10000.0, -(double)(2 * jj + 1) / 256.0);
  if (j < 128) { sinT[idx] = (float)sin(fA); cosT[idx] = (float)sin(fB); }
  else         { sinT[idx] = (float)cos(fA); cosT[idx] = (float)cos(fB); }
}

// ---------------- zero the pad rows of pK / pV --------------------------
__global__ void zero_pads_k(float* __restrict__ pK, float* __restrict__ pV) {
  int idx = blockIdx.x * blockDim.x + threadIdx.x;
  const int n = B_SZ * 2 * PAD * H_DIM;
  if (idx >= 2 * n) return;
  float* p = (idx < n) ? pK : pV;
  int r    = idx & (n - 1);
  int b    = r / (2 * PAD * H_DIM);
  int rem  = r % (2 * PAD * H_DIM);
  int side = rem / (PAD * H_DIM);
  int rr   = rem % (PAD * H_DIM);
  int row  = (side == 0) ? (rr / H_DIM) : (PAD + S_LEN + rr / H_DIM);
  int h    = rr % H_DIM;
  p[((size_t)b * SP + row) * H_DIM + h] = 0.f;
}

// ---------------- f32 -> bf16 hi/lo split (Markidis) --------------------
__global__ void conv_split_k(const float* __restrict__ in, bf16* __restrict__ hi,
                             bf16* __restrict__ lo, int n) {
  int idx = (blockIdx.x * blockDim.x + threadIdx.x) * 4;
  if (idx >= n) return;
  float4 v = *(const float4*)(in + idx);
  bf16 h0 = (bf16)v.x, h1 = (bf16)v.y, h2 = (bf16)v.z, h3 = (bf16)v.w;
  bf16 l0 = (bf16)(v.x - (float)h0), l1 = (bf16)(v.y - (float)h1);
  bf16 l2 = (bf16)(v.z - (float)h2), l3 = (bf16)(v.w - (float)h3);
  bf16x4 hv = {h0, h1, h2, h3};
  bf16x4 lv = {l0, l1, l2, l3};
  *(bf16x4*)(hi + idx) = hv;
  *(bf16x4*)(lo + idx) = lv;
}

// 4 weight matrices -> concat [2048][512] hi/lo
__global__ void conv_w_k(const float* __restrict__ Wq, const float* __restrict__ Wk,
                         const float* __restrict__ Wv, const float* __restrict__ Wo,
                         bf16* __restrict__ hi, bf16* __restrict__ lo) {
  int idx = (blockIdx.x * blockDim.x + threadIdx.x) * 4;
  if (idx >= 2048 * 512) return;
  int m = idx >> 18;
  const float* src = (m == 0) ? Wq : (m == 1) ? Wk : (m == 2) ? Wv : Wo;
  float4 v = *(const float4*)(src + (idx & 262143));
  bf16 h0 = (bf16)v.x, h1 = (bf16)v.y, h2 = (bf16)v.z, h3 = (bf16)v.w;
  bf16 l0 = (bf16)(v.x - (float)h0), l1 = (bf16)(v.y - (float)h1);
  bf16 l2 = (bf16)(v.z - (float)h2), l3 = (bf16)(v.w - (float)h3);
  bf16x4 hv = {h0, h1, h2, h3};
  bf16x4 lv = {l0, l1, l2, l3};
  *(bf16x4*)(hi + idx) = hv;
  *(bf16x4*)(lo + idx) = lv;
}

// ---------------- split-bf16 MFMA GEMM ----------------------------------
// C[M][512-chunk] = A[M][512] @ Wcat[wrow0..][512]^T (+bias, +rope epilogue)
// MODE 0: fused QKV (blockIdx.y in [0,12), region = y>>2: Q-rope, K-rope-pad, V-pad)
// MODE 1: O-proj (bias only, write oQ)
// LDS rows: 128B = [hi 32bf16 | lo 32bf16], XOR-swizzled byte ^= (row&7)<<4
template<int MFR, int MODE>
__global__ __launch_bounds__(256) void gemm_k(
    const bf16* __restrict__ Ahi, const bf16* __restrict__ Alo,
    const bf16* __restrict__ Whi, const bf16* __restrict__ Wlo,
    const float* __restrict__ bq, const float* __restrict__ bk,
    const float* __restrict__ bv,
    const float* __restrict__ sinT, const float* __restrict__ cosT,
    float* __restrict__ oQ, float* __restrict__ oK, float* __restrict__ oV)
{
  constexpr int BM = MFR * 32;
  __shared__ __align__(16) unsigned char smem[(BM + 128) * 128];
  const int tid = threadIdx.x;
  const int lane = tid & 63, wid = tid >> 6;
  const int wm = wid >> 1, wn = wid & 1;
  const int row0 = blockIdx.x * BM;
  const int wrow0 = (MODE == 0 ? 0 : 1536) + blockIdx.y * 128;
  const int lr = lane & 15, lk = lane >> 4;

  f32x4 acc[MFR][4] = {};

  for (int k0 = 0; k0 < 512; k0 += 32) {
    __syncthreads();
#pragma unroll
    for (int i = 0; i < MFR; i++) {           // stage A (BM x 32 hi+lo)
      int c = tid + i * 256;
      int r = c >> 3, slot = c & 7;
      int dst = r * 128 + (((slot * 16) ^ ((r & 7) << 4)));
      const bf16* src = (slot < 4) ? Ahi : Alo;
      float4 v = *(const float4*)(src + (size_t)(row0 + r) * 512 + k0 + (slot & 3) * 8);
      *(float4*)(smem + dst) = v;
    }
#pragma unroll
    for (int i = 0; i < 4; i++) {             // stage B (128 x 32 hi+lo)
      int c = tid + i * 256;
      int r = c >> 3, slot = c & 7;
      int dst = BM * 128 + r * 128 + (((slot * 16) ^ ((r & 7) << 4)));
      const bf16* src = (slot < 4) ? Whi : Wlo;
      float4 v = *(const float4*)(src + (size_t)(wrow0 + r) * 512 + k0 + (slot & 3) * 8);
      *(float4*)(smem + dst) = v;
    }
    __syncthreads();
    bf16x8 bfr[4][2];
#pragma unroll
    for (int ni = 0; ni < 4; ni++) {
      int r = wn * 64 + ni * 16 + lr;
      const unsigned char* base = smem + BM * 128 + r * 128;
      int sw = (r & 7) << 4;
      bfr[ni][0] = *(const bf16x8*)(base + ((lk * 16) ^ sw));
      bfr[ni][1] = *(const bf16x8*)(base + ((64 + lk * 16) ^ sw));
    }
#pragma unroll
    for (int mi = 0; mi < MFR; mi++) {
      int r = wm * (MFR * 16) + mi * 16 + lr;
      const unsigned char* base = smem + r * 128;
      int sw = (r & 7) << 4;
      bf16x8 ah = *(const bf16x8*)(base + ((lk * 16) ^ sw));
      bf16x8 al = *(const bf16x8*)(base + ((64 + lk * 16) ^ sw));
#pragma unroll
      for (int ni = 0; ni < 4; ni++) {
        acc[mi][ni] = __builtin_amdgcn_mfma_f32_16x16x32_bf16(ah, bfr[ni][0], acc[mi][ni], 0, 0, 0);
        acc[mi][ni] = __builtin_amdgcn_mfma_f32_16x16x32_bf16(ah, bfr[ni][1], acc[mi][ni], 0, 0, 0);
        acc[mi][ni] = __builtin_amdgcn_mfma_f32_16x16x32_bf16(al, bfr[ni][0], acc[mi][ni], 0, 0, 0);
      }
    }
  }

  // ---- epilogue: C row = row0 + wm*MFR*16 + mi*16 + (lane>>4)*4 + g
  //                C col = colbase + wn*64 + ni*16 + (lane&15)
  const int rowb = row0 + wm * (MFR * 16) + ((lane >> 4) * 4);
  if (MODE == 1) {
#pragma unroll
    for (int mi = 0; mi < MFR; mi++)
#pragma unroll
      for (int ni = 0; ni < 4; ni++) {
        int col = blockIdx.y * 128 + wn * 64 + ni * 16 + (lane & 15);
        float bb = bq[col];
#pragma unroll
        for (int g = 0; g < 4; g++) {
          int rr = rowb + mi * 16 + g;
          oQ[(size_t)rr * 512 + col] = acc[mi][ni][g] + bb;
        }
      }
    return;
  }
  const int region = blockIdx.y >> 2;                 // 0=Q 1=K 2=V (uniform)
  const float* bias = (region == 0) ? bq : (region == 1) ? bk : bv;
  const int cm0 = (blockIdx.y & 3) * 128;
#pragma unroll
  for (int mi = 0; mi < MFR; mi++)
#pragma unroll
    for (int ni = 0; ni < 4; ni++) {
      int c = cm0 + wn * 64 + ni * 16 + (lane & 15);  // col within its 512 matrix
      float bb = bias[c];
      if (region == 2) {
#pragma unroll
        for (int g = 0; g < 4; g++) {
          int rr = rowb + mi * 16 + g;
          int b = rr >> 11, s = rr & 2047;
          oV[((size_t)b * SP + PAD + s) * 512 + c] = acc[mi][ni][g] + bb;
        }
      } else {
        int j = c >> 1, par = c & 1;
#pragma unroll
        for (int g = 0; g < 4; g++) {
          int rr = rowb + mi * 16 + g;
          int s = rr & 2047;
          float v = acc[mi][ni][g] + bb;
          float p = __shfl_xor(v, 1);                 // partner col (2j<->2j+1)
          float es = sinT[s * 256 + j], ec = cosT[s * 256 + j];
          float res = par ? (p * es + v * ec) : (v * ec - p * es);
          int oc = par ? (j + 256) : j;
          if (region == 0) oQ[(size_t)rr * 512 + oc] = res;
          else { int b = rr >> 11; oK[((size_t)b * SP + PAD + s) * 512 + oc] = res; }
        }
      }
    }
}

// ---------------- windowed attention, one block per query ---------------
__global__ __launch_bounds__(256) void attn_k(const float* __restrict__ rQ,
    const float* __restrict__ pK, const float* __restrict__ pV,
    float* __restrict__ out) {
  int bq = blockIdx.x;
  int b = bq >> 11, s = bq & (S_LEN - 1);
  int tid = threadIdx.x;
  __shared__ __align__(16) float qs[H_DIM];
  __shared__ float sc2[2][WIN];
  __shared__ float sc[WIN];
  __shared__ float redm[4], reds[4];
  const float* qrow = rQ + (size_t)bq * H_DIM;
  qs[tid]       = qrow[tid];
  qs[tid + 256] = qrow[tid + 256];
  __syncthreads();
  int w = tid & (WIN - 1), half = tid >> 7;
  const float4* k4 = (const float4*)(pK + ((size_t)(b * SP + s + w)) * H_DIM + half * 256);
  const float4* q4 = (const float4*)(qs + half * 256);
  float p0 = 0.f, p1 = 0.f, p2 = 0.f, p3 = 0.f;
#pragma unroll
  for (int i = 0; i < 64; i += 4) {
    float4 k0v = k4[i],     q0v = q4[i];
    float4 k1v = k4[i + 1], q1v = q4[i + 1];
    float4 k2v = k4[i + 2], q2v = q4[i + 2];
    float4 k3v = k4[i + 3], q3v = q4[i + 3];
    p0 += q0v.x * k0v.x + q0v.y * k0v.y + q0v.z * k0v.z + q0v.w * k0v.w;
    p1 += q1v.x * k1v.x + q1v.y * k1v.y + q1v.z * k1v.z + q1v.w * k1v.w;
    p2 += q2v.x * k2v.x + q2v.y * k2v.y + q2v.z * k2v.z + q2v.w * k2v.w;
    p3 += q3v.x * k3v.x + q3v.y * k3v.y + q3v.z * k3v.z + q3v.w * k3v.w;
  }
  sc2[half][w] = (p0 + p1) + (p2 + p3);
  __syncthreads();
  float sval = -1e30f;
  if (tid < WIN) sval = (sc2[0][tid] + sc2[1][tid]) * SCALE;
  float m = sval;
#pragma unroll
  for (int off = 32; off; off >>= 1) m = fmaxf(m, __shfl_xor(m, off));
  if ((tid & 63) == 0) redm[tid >> 6] = m;
  __syncthreads();
  m = fmaxf(fmaxf(redm[0], redm[1]), fmaxf(redm[2], redm[3]));
  float e = (tid < WIN) ? expf(sval - m) : 0.f;
  float ssum = e;
#pragma unroll
  for (int off = 32; off; off >>= 1) ssum += __shfl_xor(ssum, off);
  if ((tid & 63) == 0) reds[tid >> 6] = ssum;
  __syncthreads();
  float tot = reds[0] + reds[1] + reds[2] + reds[3];
  if (tid < WIN) sc[tid] = e / tot;
  __syncthreads();
  const float* vbase = pV + (size_t)(b * SP + s) * H_DIM;
  float a0 = 0.f, a1 = 0.f, a2 = 0.f, a3 = 0.f;
  float a4 = 0.f, a5 = 0.f, a6 = 0.f, a7 = 0.f;
  for (int ww = 0; ww < 128; ww += 4) {
    float w0 = sc[ww], w1 = sc[ww + 1], w2 = sc[ww + 2], w3 = sc[ww + 3];
    const float* v0 = vbase + (size_t)ww * 512;
    a0 += w0 * v0[tid];          a1 += w0 * v0[tid + 256];
    a2 += w1 * v0[512 + tid];    a3 += w1 * v0[512 + tid + 256];
    a4 += w2 * v0[1024 + tid];   a5 += w2 * v0[1024 + tid + 256];
    a6 += w3 * v0[1536 + tid];   a7 += w3 * v0[1536 + tid + 256];
  }
  out[(size_t)bq * H_DIM + tid]       = (a0 + a2) + (a4 + a6);
  out[(size_t)bq * H_DIM + 256 + tid] = (a1 + a3) + (a5 + a7);
}

// ---------------- launch -------------------------------------------------
extern "C" void kernel_launch(void* const* d_in, const int* in_sizes, int n_in,
                              void* d_out, int out_size, void* d_ws, size_t ws_size,
                              hipStream_t stream) {
  const float* x  = (const float*)d_in[0];
  const float* Wq = (const float*)d_in[1];
  const float* bq = (const float*)d_in[2];
  const float* Wk = (const float*)d_in[3];
  const float* bk = (const float*)d_in[4];
  const float* Wv = (const float*)d_in[5];
  const float* bv = (const float*)d_in[6];
  const float* Wo = (const float*)d_in[7];
  const float* bo = (const float*)d_in[8];
  float* out = (float*)d_out;

  const size_t NQ = (size_t)B_SZ * S_LEN * H_DIM;  // 2,097,152
  const size_t NP = (size_t)B_SZ * SP * H_DIM;     // 2,228,224
  float* ws   = (float*)d_ws;
  float* rQ   = ws;                                // NQ f32
  float* attn = rQ + NQ;                           // NQ f32
  float* pK   = attn + NQ;                         // NP f32
  float* pV   = pK + NP;                           // NP f32
  float* sinT = pV + NP;                           // 524288 f32
  float* cosT = sinT + (size_t)S_LEN * 256;        // 524288 f32
  bf16* xhi = (bf16*)(cosT + (size_t)S_LEN * 256); // NQ bf16
  bf16* xlo = xhi + NQ;                            // NQ bf16
  bf16* whi = xlo + NQ;                            // 2048*512 bf16
  bf16* wlo = whi + 2048 * 512;                    // 2048*512 bf16
  bf16* ahi = wlo + 2048 * 512;                    // NQ bf16
  bf16* alo = ahi + NQ;                            // NQ bf16
  // total ~59.8 MB

  rope_tables_k<<<(S_LEN * 256 + 255) / 256, 256, 0, stream>>>(sinT, cosT);
  zero_pads_k<<<(2 * B_SZ * 2 * PAD * H_DIM + 255) / 256, 256, 0, stream>>>(pK, pV);
  conv_split_k<<<(int)(NQ / 4 / 256), 256, 0, stream>>>(x, xhi, xlo, (int)NQ);
  conv_w_k<<<2048 * 512 / 4 / 256, 256, 0, stream>>>(Wq, Wk, Wv, Wo, whi, wlo);

  gemm_k<4, 0><<<dim3(32, 12), 256, 0, stream>>>(xhi, xlo, whi, wlo,
      bq, bk, bv, sinT, cosT, rQ, pK, pV);

  attn_k<<<B_SZ * S_LEN, 256, 0, stream>>>(rQ, pK, pV, attn);

  conv_split_k<<<(int)(NQ / 4 / 256), 256, 0, stream>>>(attn, ahi, alo, (int)NQ);

  gemm_k<2, 1><<<dim3(64, 4), 256, 0, stream>>>(ahi, alo, whi, wlo,
      bo, nullptr, nullptr, sinT, cosT, out, nullptr, nullptr);
}

// Round 3
// 86.766 us; speedup vs baseline: 4.4420x; 2.6834x over previous
//
#include <hip/hip_runtime.h>
#include <math.h>

#define S_LEN 2048
#define B_SZ  2
#define H_DIM 512
#define WIN   128
#define PAD   64
#define SP    (S_LEN + WIN)   /* 2176 padded seq length */
#define SCALE 0.044194173824159216f  /* 1/sqrt(512) */
#define TQ    32
#define KU    160

typedef __bf16 bf16;
typedef __attribute__((ext_vector_type(8))) __bf16 bf16x8;
typedef __attribute__((ext_vector_type(4))) __bf16 bf16x4;
typedef __attribute__((ext_vector_type(4))) float f32x4;

// ---------------- RoPE tables (f64 on device; verified) -----------------
__global__ void rope_tables_k(float* __restrict__ sinT, float* __restrict__ cosT) {
  int idx = blockIdx.x * blockDim.x + threadIdx.x;
  if (idx >= S_LEN * 256) return;
  int s = idx >> 8, j = idx & 255;
  int jj = j & 127;
  double t  = (double)s;
  double fA = t * pow(10000.0, -(double)jj / 128.0);
  double fB = t * pow(10000.0, -(double)(2 * jj + 1) / 256.0);
  if (j < 128) { sinT[idx] = (float)sin(fA); cosT[idx] = (float)sin(fB); }
  else         { sinT[idx] = (float)cos(fA); cosT[idx] = (float)cos(fB); }
}

// ---------------- zero pads of bf16 pK (row-pad) and pVT (col-pad) ------
__global__ void pad_zero_k(bf16* __restrict__ pKb, bf16* __restrict__ pVT) {
  int idx = blockIdx.x * blockDim.x + threadIdx.x;   // [0, 32768) float4-slots
  float4 z = {0.f, 0.f, 0.f, 0.f};
  if (idx < 16384) {          // pKb: 2b x 128 pad-rows x 512 cols
    int b = idx >> 13, r = (idx & 8191) >> 6, c = idx & 63;
    int row = (r < 64) ? r : (S_LEN + r);            // rows 0..63 and 2112..2175
    *(float4*)(pKb + ((size_t)b * SP + row) * 512 + c * 8) = z;
  } else {                    // pVT: 2b x 512 rows x 128 pad-cols
    int j = idx - 16384;
    int b = j >> 13, h = (j & 8191) >> 4, v = j & 15;
    int col = (v < 8) ? v * 8 : (S_LEN + PAD + (v - 8) * 8);
    *(float4*)(pVT + ((size_t)b * 512 + h) * SP + col) = z;
  }
}

// ---------------- f32 -> bf16 hi/lo split (Markidis) --------------------
__global__ void conv_split_k(const float* __restrict__ in, bf16* __restrict__ hi,
                             bf16* __restrict__ lo, int n) {
  int idx = (blockIdx.x * blockDim.x + threadIdx.x) * 4;
  if (idx >= n) return;
  float4 v = *(const float4*)(in + idx);
  bf16 h0 = (bf16)v.x, h1 = (bf16)v.y, h2 = (bf16)v.z, h3 = (bf16)v.w;
  bf16 l0 = (bf16)(v.x - (float)h0), l1 = (bf16)(v.y - (float)h1);
  bf16 l2 = (bf16)(v.z - (float)h2), l3 = (bf16)(v.w - (float)h3);
  bf16x4 hv = {h0, h1, h2, h3};
  bf16x4 lv = {l0, l1, l2, l3};
  *(bf16x4*)(hi + idx) = hv;
  *(bf16x4*)(lo + idx) = lv;
}

// 4 weight matrices -> concat [2048][512] hi/lo
__global__ void conv_w_k(const float* __restrict__ Wq, const float* __restrict__ Wk,
                         const float* __restrict__ Wv, const float* __restrict__ Wo,
                         bf16* __restrict__ hi, bf16* __restrict__ lo) {
  int idx = (blockIdx.x * blockDim.x + threadIdx.x) * 4;
  if (idx >= 2048 * 512) return;
  int m = idx >> 18;
  const float* src = (m == 0) ? Wq : (m == 1) ? Wk : (m == 2) ? Wv : Wo;
  float4 v = *(const float4*)(src + (idx & 262143));
  bf16 h0 = (bf16)v.x, h1 = (bf16)v.y, h2 = (bf16)v.z, h3 = (bf16)v.w;
  bf16 l0 = (bf16)(v.x - (float)h0), l1 = (bf16)(v.y - (float)h1);
  bf16 l2 = (bf16)(v.z - (float)h2), l3 = (bf16)(v.w - (float)h3);
  bf16x4 hv = {h0, h1, h2, h3};
  bf16x4 lv = {l0, l1, l2, l3};
  *(bf16x4*)(hi + idx) = hv;
  *(bf16x4*)(lo + idx) = lv;
}

// ---------------- split-bf16 MFMA GEMM ----------------------------------
// MODE 0: fused QKV -> bf16 rQ (rope), bf16 pK (rope+pad), bf16 pVT (transposed+pad)
// MODE 1: O-proj -> f32 out (bias from bq slot)
template<int MFR, int MODE>
__global__ __launch_bounds__(256) void gemm_k(
    const bf16* __restrict__ Ahi, const bf16* __restrict__ Alo,
    const bf16* __restrict__ Whi, const bf16* __restrict__ Wlo,
    const float* __restrict__ bq, const float* __restrict__ bk,
    const float* __restrict__ bv,
    const float* __restrict__ sinT, const float* __restrict__ cosT,
    bf16* __restrict__ oQ, bf16* __restrict__ oK, bf16* __restrict__ oVT,
    float* __restrict__ oOut)
{
  constexpr int BM = MFR * 32;
  __shared__ __align__(16) unsigned char smem[(BM + 128) * 128];
  const int tid = threadIdx.x;
  const int lane = tid & 63, wid = tid >> 6;
  const int wm = wid >> 1, wn = wid & 1;
  const int row0 = blockIdx.x * BM;
  const int wrow0 = (MODE == 0 ? 0 : 1536) + blockIdx.y * 128;
  const int lr = lane & 15, lk = lane >> 4;

  f32x4 acc[MFR][4] = {};

  for (int k0 = 0; k0 < 512; k0 += 32) {
    __syncthreads();
#pragma unroll
    for (int i = 0; i < MFR; i++) {           // stage A (BM x 32 hi+lo)
      int c = tid + i * 256;
      int r = c >> 3, slot = c & 7;
      int dst = r * 128 + (((slot * 16) ^ ((r & 7) << 4)));
      const bf16* src = (slot < 4) ? Ahi : Alo;
      float4 v = *(const float4*)(src + (size_t)(row0 + r) * 512 + k0 + (slot & 3) * 8);
      *(float4*)(smem + dst) = v;
    }
#pragma unroll
    for (int i = 0; i < 4; i++) {             // stage B (128 x 32 hi+lo)
      int c = tid + i * 256;
      int r = c >> 3, slot = c & 7;
      int dst = BM * 128 + r * 128 + (((slot * 16) ^ ((r & 7) << 4)));
      const bf16* src = (slot < 4) ? Whi : Wlo;
      float4 v = *(const float4*)(src + (size_t)(wrow0 + r) * 512 + k0 + (slot & 3) * 8);
      *(float4*)(smem + dst) = v;
    }
    __syncthreads();
    bf16x8 bfr[4][2];
#pragma unroll
    for (int ni = 0; ni < 4; ni++) {
      int r = wn * 64 + ni * 16 + lr;
      const unsigned char* base = smem + BM * 128 + r * 128;
      int sw = (r & 7) << 4;
      bfr[ni][0] = *(const bf16x8*)(base + ((lk * 16) ^ sw));
      bfr[ni][1] = *(const bf16x8*)(base + ((64 + lk * 16) ^ sw));
    }
#pragma unroll
    for (int mi = 0; mi < MFR; mi++) {
      int r = wm * (MFR * 16) + mi * 16 + lr;
      const unsigned char* base = smem + r * 128;
      int sw = (r & 7) << 4;
      bf16x8 ah = *(const bf16x8*)(base + ((lk * 16) ^ sw));
      bf16x8 al = *(const bf16x8*)(base + ((64 + lk * 16) ^ sw));
#pragma unroll
      for (int ni = 0; ni < 4; ni++) {
        acc[mi][ni] = __builtin_amdgcn_mfma_f32_16x16x32_bf16(ah, bfr[ni][0], acc[mi][ni], 0, 0, 0);
        acc[mi][ni] = __builtin_amdgcn_mfma_f32_16x16x32_bf16(ah, bfr[ni][1], acc[mi][ni], 0, 0, 0);
        acc[mi][ni] = __builtin_amdgcn_mfma_f32_16x16x32_bf16(al, bfr[ni][0], acc[mi][ni], 0, 0, 0);
      }
    }
  }

  const int rowb = row0 + wm * (MFR * 16) + ((lane >> 4) * 4);
  if (MODE == 1) {
#pragma unroll
    for (int mi = 0; mi < MFR; mi++)
#pragma unroll
      for (int ni = 0; ni < 4; ni++) {
        int col = blockIdx.y * 128 + wn * 64 + ni * 16 + (lane & 15);
        float bb = bq[col];
#pragma unroll
        for (int g = 0; g < 4; g++) {
          int rr = rowb + mi * 16 + g;
          oOut[(size_t)rr * 512 + col] = acc[mi][ni][g] + bb;
        }
      }
    return;
  }
  const int region = blockIdx.y >> 2;                 // 0=Q 1=K 2=V
  const float* bias = (region == 0) ? bq : (region == 1) ? bk : bv;
  const int cm0 = (blockIdx.y & 3) * 128;
#pragma unroll
  for (int mi = 0; mi < MFR; mi++)
#pragma unroll
    for (int ni = 0; ni < 4; ni++) {
      int c = cm0 + wn * 64 + ni * 16 + (lane & 15);
      float bb = bias[c];
      if (region == 2) {
#pragma unroll
        for (int g = 0; g < 4; g++) {
          int rr = rowb + mi * 16 + g;
          int b = rr >> 11, s = rr & 2047;
          oVT[((size_t)b * 512 + c) * SP + PAD + s] = (bf16)(acc[mi][ni][g] + bb);
        }
      } else {
        int j = c >> 1, par = c & 1;
#pragma unroll
        for (int g = 0; g < 4; g++) {
          int rr = rowb + mi * 16 + g;
          int s = rr & 2047;
          float v = acc[mi][ni][g] + bb;
          float p = __shfl_xor(v, 1);
          float es = sinT[s * 256 + j], ec = cosT[s * 256 + j];
          float res = par ? (p * es + v * ec) : (v * ec - p * es);
          int oc = par ? (j + 256) : j;
          if (region == 0) oQ[(size_t)rr * 512 + oc] = (bf16)res;
          else { int b = rr >> 11; oK[((size_t)b * SP + PAD + s) * 512 + oc] = (bf16)res; }
        }
      }
    }
}

// ---------------- banded MFMA attention ---------------------------------
// One block = 32 queries (q0..q0+31), key-union = 160 padded keys.
// Phase 1: S = Q K^T (8 LDS-staged K-chunks of 64)
// Phase 2: banded softmax (valid iff i <= j <= i+127), P -> bf16 LDS
// Phase 3: out = P V via pVT (h-major), 4 chunks of 128 h-cols
// LDS: [0,24576) Q+K staging  |  [0,20992) scores  |  [0,43008) V chunk
//      [43008,53760) P  (disjoint from all reused regions)
__global__ __launch_bounds__(256) void attn_mfma_k(
    const bf16* __restrict__ rQb, const bf16* __restrict__ pKb,
    const bf16* __restrict__ pVT, bf16* __restrict__ ahi, bf16* __restrict__ alo)
{
  __shared__ __align__(16) unsigned char smem[53760];
  const int tid = threadIdx.x, lane = tid & 63, w = tid >> 6;
  const int q0g = blockIdx.x * TQ;
  const int b = q0g >> 11, s0 = q0g & 2047;
  const int lr = lane & 15, lk = lane >> 4;
  const int OFF_K = 4096, OFF_P = 43008;

  // ---- phase 1: scores
  f32x4 sacc[5] = {};
  const int tm = w >> 1, tnb = (w & 1) * 5;
  for (int k0 = 0; k0 < 512; k0 += 64) {
    __syncthreads();
    {
      int r = tid >> 3, slot = tid & 7;
      float4 v = *(const float4*)(rQb + (size_t)(q0g + r) * 512 + k0 + slot * 8);
      *(float4*)(smem + r * 128 + (((slot * 16) ^ ((r & 7) << 4)))) = v;
    }
#pragma unroll
    for (int i = 0; i < 5; i++) {
      int c = tid + i * 256;
      int r = c >> 3, slot = c & 7;
      float4 v = *(const float4*)(pKb + ((size_t)b * SP + s0 + r) * 512 + k0 + slot * 8);
      *(float4*)(smem + OFF_K + r * 128 + (((slot * 16) ^ ((r & 7) << 4)))) = v;
    }
    __syncthreads();
#pragma unroll
    for (int kk = 0; kk < 2; kk++) {
      int arow = tm * 16 + lr;
      bf16x8 a = *(const bf16x8*)(smem + arow * 128 + (((kk * 64 + lk * 16) ^ ((arow & 7) << 4))));
#pragma unroll
      for (int i = 0; i < 5; i++) {
        int brow = (tnb + i) * 16 + lr;
        bf16x8 bb = *(const bf16x8*)(smem + OFF_K + brow * 128 + (((kk * 64 + lk * 16) ^ ((brow & 7) << 4))));
        sacc[i] = __builtin_amdgcn_mfma_f32_16x16x32_bf16(a, bb, sacc[i], 0, 0, 0);
      }
    }
  }
  __syncthreads();
  {   // write scores f32 [32][164]
    float* sc = (float*)smem;
#pragma unroll
    for (int i = 0; i < 5; i++) {
      int col = (tnb + i) * 16 + lr;
#pragma unroll
      for (int g = 0; g < 4; g++) {
        int row = tm * 16 + lk * 4 + g;
        sc[row * 164 + col] = sacc[i][g] * SCALE;
      }
    }
  }
  __syncthreads();
  // ---- phase 2: banded softmax, 8 threads per row
  {
    float* sc = (float*)smem;
    bf16* P = (bf16*)(smem + OFF_P);
    int row = tid >> 3, j0 = tid & 7;
    float vals[20];
    float mx = -1e30f;
#pragma unroll
    for (int i = 0; i < 20; i++) {
      int j = j0 + i * 8;
      bool valid = (j >= row) && (j <= row + 127);
      float v = valid ? sc[row * 164 + j] : -1e30f;
      vals[i] = v;
      mx = fmaxf(mx, v);
    }
#pragma unroll
    for (int off = 1; off < 8; off <<= 1) mx = fmaxf(mx, __shfl_xor(mx, off));
    float sum = 0.f;
#pragma unroll
    for (int i = 0; i < 20; i++) {
      float e = (vals[i] > -1e29f) ? __expf(vals[i] - mx) : 0.f;
      vals[i] = e; sum += e;
    }
#pragma unroll
    for (int off = 1; off < 8; off <<= 1) sum += __shfl_xor(sum, off);
    float inv = 1.f / sum;
#pragma unroll
    for (int i = 0; i < 20; i++) {
      int j = j0 + i * 8;
      P[row * 168 + j] = (bf16)(vals[i] * inv);   // row stride 336B
    }
  }
  // ---- phase 3: out = P @ V
  const bf16* pVTb = pVT + (size_t)b * 512 * SP;
  const int utm = w >> 1, utnb = (w & 1) * 4;
  for (int n0 = 0; n0 < 512; n0 += 128) {
    __syncthreads();
    {   // stage V chunk: 128 h-rows x 160 keys, LDS row stride 336B
      int r = tid >> 1, half = tid & 1;
      const bf16* src = pVTb + (size_t)(n0 + r) * SP + s0;
#pragma unroll
      for (int i = 0; i < 10; i++) {
        int slot = half * 10 + i;
        float4 v = *(const float4*)(src + slot * 8);
        *(float4*)(smem + r * 336 + slot * 16) = v;
      }
    }
    __syncthreads();
    f32x4 oacc[4] = {};
#pragma unroll
    for (int tk = 0; tk < 5; tk++) {
      int arow = utm * 16 + lr;
      bf16x8 a = *(const bf16x8*)(smem + OFF_P + arow * 336 + tk * 64 + lk * 16);
#pragma unroll
      for (int i = 0; i < 4; i++) {
        int brow = (utnb + i) * 16 + lr;
        bf16x8 bb = *(const bf16x8*)(smem + brow * 336 + tk * 64 + lk * 16);
        oacc[i] = __builtin_amdgcn_mfma_f32_16x16x32_bf16(a, bb, oacc[i], 0, 0, 0);
      }
    }
#pragma unroll
    for (int i = 0; i < 4; i++) {
      int col = n0 + (utnb + i) * 16 + lr;
#pragma unroll
      for (int g = 0; g < 4; g++) {
        int row = utm * 16 + lk * 4 + g;
        float v = oacc[i][g];
        bf16 h = (bf16)v;
        size_t idx = (size_t)(q0g + row) * 512 + col;
        ahi[idx] = h;
        alo[idx] = (bf16)(v - (float)h);
      }
    }
  }
}

// ---------------- launch -------------------------------------------------
extern "C" void kernel_launch(void* const* d_in, const int* in_sizes, int n_in,
                              void* d_out, int out_size, void* d_ws, size_t ws_size,
                              hipStream_t stream) {
  const float* x  = (const float*)d_in[0];
  const float* Wq = (const float*)d_in[1];
  const float* bq = (const float*)d_in[2];
  const float* Wk = (const float*)d_in[3];
  const float* bk = (const float*)d_in[4];
  const float* Wv = (const float*)d_in[5];
  const float* bv = (const float*)d_in[6];
  const float* Wo = (const float*)d_in[7];
  const float* bo = (const float*)d_in[8];
  float* out = (float*)d_out;

  const size_t NQ = (size_t)B_SZ * S_LEN * H_DIM;  // 2,097,152
  const size_t NP = (size_t)B_SZ * SP * H_DIM;     // 2,228,224
  float* sinT = (float*)d_ws;                      // 524288 f32
  float* cosT = sinT + (size_t)S_LEN * 256;        // 524288 f32
  bf16* xhi = (bf16*)(cosT + (size_t)S_LEN * 256); // NQ
  bf16* xlo = xhi + NQ;                            // NQ
  bf16* whi = xlo + NQ;                            // 1M
  bf16* wlo = whi + 2048 * 512;                    // 1M
  bf16* rQb = wlo + 2048 * 512;                    // NQ
  bf16* pKb = rQb + NQ;                            // NP
  bf16* pVT = pKb + NP;                            // NP
  bf16* ahi = pVT + NP;                            // NQ
  bf16* alo = ahi + NQ;                            // NQ
  // total ~37 MB

  rope_tables_k<<<(S_LEN * 256 + 255) / 256, 256, 0, stream>>>(sinT, cosT);
  pad_zero_k<<<128, 256, 0, stream>>>(pKb, pVT);
  conv_split_k<<<(int)(NQ / 4 / 256), 256, 0, stream>>>(x, xhi, xlo, (int)NQ);
  conv_w_k<<<2048 * 512 / 4 / 256, 256, 0, stream>>>(Wq, Wk, Wv, Wo, whi, wlo);

  gemm_k<4, 0><<<dim3(32, 12), 256, 0, stream>>>(xhi, xlo, whi, wlo,
      bq, bk, bv, sinT, cosT, rQb, pKb, pVT, nullptr);

  attn_mfma_k<<<B_SZ * S_LEN / TQ, 256, 0, stream>>>(rQb, pKb, pVT, ahi, alo);

  gemm_k<2, 1><<<dim3(64, 4), 256, 0, stream>>>(ahi, alo, whi, wlo,
      bo, nullptr, nullptr, sinT, cosT, nullptr, nullptr, nullptr, out);
}

// Round 4
// 77.111 us; speedup vs baseline: 4.9981x; 1.1252x over previous
//
#include <hip/hip_runtime.h>
#include <math.h>

#define S_LEN 2048
#define B_SZ  2
#define H_DIM 512
#define WIN   128
#define PAD   64
#define SP    (S_LEN + WIN)   /* 2176 padded seq length */
#define SCALE 0.044194173824159216f  /* 1/sqrt(512) */
#define TQ    32

typedef __bf16 bf16;
typedef __attribute__((ext_vector_type(8))) __bf16 bf16x8;
typedef __attribute__((ext_vector_type(4))) __bf16 bf16x4;
typedef __attribute__((ext_vector_type(4))) float f32x4;

#define GLDS16(g, l) __builtin_amdgcn_global_load_lds( \
    (const __attribute__((address_space(1))) void*)(g), \
    (__attribute__((address_space(3))) void*)(l), 16, 0, 0)

// ---------------- RoPE tables -------------------------------------------
__global__ void rope_freq_k(double* __restrict__ freq) {
  int i = threadIdx.x;   // 512
  if (i < 512) freq[i] = pow(10000.0, -(double)i / 256.0);
}
// thread = (s, jj) ; writes sin/cos pairs for freq 2jj (sinT) and 2jj+1 (cosT)
__global__ void rope_tables_k(const double* __restrict__ freq,
                              float* __restrict__ sinT, float* __restrict__ cosT) {
  int idx = blockIdx.x * blockDim.x + threadIdx.x;
  if (idx >= S_LEN * 128) return;
  int s = idx >> 7, jj = idx & 127;
  double t = (double)s;
  const double inv2pi = 0.15915494309189535;
  const double twopi  = 6.283185307179586;
  double fA = t * freq[2 * jj];
  double fB = t * freq[2 * jj + 1];
  float ra = (float)(fA - rint(fA * inv2pi) * twopi);
  float rb = (float)(fB - rint(fB * inv2pi) * twopi);
  sinT[s * 256 + jj]       = sinf(ra);
  sinT[s * 256 + jj + 128] = cosf(ra);
  cosT[s * 256 + jj]       = sinf(rb);
  cosT[s * 256 + jj + 128] = cosf(rb);
}

// ---------------- zero pads of bf16 pK (row-pad) and pVT (col-pad) ------
__global__ void pad_zero_k(bf16* __restrict__ pKb, bf16* __restrict__ pVT) {
  int idx = blockIdx.x * blockDim.x + threadIdx.x;   // [0, 32768) float4-slots
  float4 z = {0.f, 0.f, 0.f, 0.f};
  if (idx < 16384) {          // pKb: 2b x 128 pad-rows x 512 cols
    int b = idx >> 13, r = (idx & 8191) >> 6, c = idx & 63;
    int row = (r < 64) ? r : (S_LEN + r);
    *(float4*)(pKb + ((size_t)b * SP + row) * 512 + c * 8) = z;
  } else {                    // pVT: 2b x 512 rows x 128 pad-cols
    int j = idx - 16384;
    int b = j >> 13, h = (j & 8191) >> 4, v = j & 15;
    int col = (v < 8) ? v * 8 : (S_LEN + PAD + (v - 8) * 8);
    *(float4*)(pVT + ((size_t)b * 512 + h) * SP + col) = z;
  }
}

// ---------------- f32 -> bf16 hi/lo split (Markidis) --------------------
__global__ void conv_split_k(const float* __restrict__ in, bf16* __restrict__ hi,
                             bf16* __restrict__ lo, int n) {
  int idx = (blockIdx.x * blockDim.x + threadIdx.x) * 4;
  if (idx >= n) return;
  float4 v = *(const float4*)(in + idx);
  bf16 h0 = (bf16)v.x, h1 = (bf16)v.y, h2 = (bf16)v.z, h3 = (bf16)v.w;
  bf16 l0 = (bf16)(v.x - (float)h0), l1 = (bf16)(v.y - (float)h1);
  bf16 l2 = (bf16)(v.z - (float)h2), l3 = (bf16)(v.w - (float)h3);
  bf16x4 hv = {h0, h1, h2, h3};
  bf16x4 lv = {l0, l1, l2, l3};
  *(bf16x4*)(hi + idx) = hv;
  *(bf16x4*)(lo + idx) = lv;
}

// 4 weight matrices -> concat [2048][512] hi/lo
__global__ void conv_w_k(const float* __restrict__ Wq, const float* __restrict__ Wk,
                         const float* __restrict__ Wv, const float* __restrict__ Wo,
                         bf16* __restrict__ hi, bf16* __restrict__ lo) {
  int idx = (blockIdx.x * blockDim.x + threadIdx.x) * 4;
  if (idx >= 2048 * 512) return;
  int m = idx >> 18;
  const float* src = (m == 0) ? Wq : (m == 1) ? Wk : (m == 2) ? Wv : Wo;
  float4 v = *(const float4*)(src + (idx & 262143));
  bf16 h0 = (bf16)v.x, h1 = (bf16)v.y, h2 = (bf16)v.z, h3 = (bf16)v.w;
  bf16 l0 = (bf16)(v.x - (float)h0), l1 = (bf16)(v.y - (float)h1);
  bf16 l2 = (bf16)(v.z - (float)h2), l3 = (bf16)(v.w - (float)h3);
  bf16x4 hv = {h0, h1, h2, h3};
  bf16x4 lv = {l0, l1, l2, l3};
  *(bf16x4*)(hi + idx) = hv;
  *(bf16x4*)(lo + idx) = lv;
}

// ---------------- split-bf16 MFMA GEMM (gload_lds + 2-phase prefetch) ----
// MODE 0: fused QKV -> bf16 rQ (rope), bf16 pK (rope+pad), bf16 pVT (transposed+pad)
// MODE 1: O-proj -> f32 out (bias from bq slot)
// LDS rows: 128B = [hi 32bf16 | lo 32bf16], physical slot p holds logical
// l = p ^ (r&7)  (inverse-swizzled global source, linear gload_lds dest).
template<int MFR, int MODE>
__global__ __launch_bounds__(256) void gemm_k(
    const bf16* __restrict__ Ahi, const bf16* __restrict__ Alo,
    const bf16* __restrict__ Whi, const bf16* __restrict__ Wlo,
    const float* __restrict__ bq, const float* __restrict__ bk,
    const float* __restrict__ bv,
    const float* __restrict__ sinT, const float* __restrict__ cosT,
    bf16* __restrict__ oQ, bf16* __restrict__ oK, bf16* __restrict__ oVT,
    float* __restrict__ oOut)
{
  constexpr int BM = MFR * 32;
  constexpr int BUFB = (BM + 128) * 128;
  __shared__ __align__(16) unsigned char smem[2 * BUFB];
  const int tid = threadIdx.x;
  const int lane = tid & 63, wid = tid >> 6;
  const int wm = wid >> 1, wn = wid & 1;
  const int row0 = blockIdx.x * BM;
  const int wrow0 = (MODE == 0 ? 0 : 1536) + blockIdx.y * 128;
  const int lr = lane & 15, lk = lane >> 4;

  f32x4 acc[MFR][4] = {};

  // precomputed per-thread staging geometry
  const int rA = tid >> 3, pA = tid & 7, lA = pA ^ (rA & 7);

  auto stage = [&](int k0, int bufsel) {
    unsigned char* buf = smem + bufsel * BUFB;
#pragma unroll
    for (int i = 0; i < MFR; i++) {
      int c = tid + i * 256;
      int r = c >> 3, p = c & 7, l = p ^ (r & 7);
      const bf16* src = ((l < 4) ? Ahi : Alo) + (size_t)(row0 + r) * 512 + k0 + (l & 3) * 8;
      GLDS16(src, buf + (i * 256 + wid * 64) * 16);
    }
#pragma unroll
    for (int j = 0; j < 4; j++) {
      int c = tid + j * 256;
      int r = c >> 3, p = c & 7, l = p ^ (r & 7);
      const bf16* src = ((l < 4) ? Whi : Wlo) + (size_t)(wrow0 + r) * 512 + k0 + (l & 3) * 8;
      GLDS16(src, buf + BM * 128 + (j * 256 + wid * 64) * 16);
    }
  };
  (void)rA; (void)pA; (void)lA;

  stage(0, 0);
  __syncthreads();
  for (int t = 0; t < 16; t++) {
    if (t < 15) stage((t + 1) * 32, (t + 1) & 1);
    const unsigned char* buf = smem + (t & 1) * BUFB;
    bf16x8 bfr[4][2];
#pragma unroll
    for (int ni = 0; ni < 4; ni++) {
      int r = wn * 64 + ni * 16 + lr;
      const unsigned char* base = buf + BM * 128 + r * 128;
      int sw = (r & 7) << 4;
      bfr[ni][0] = *(const bf16x8*)(base + ((lk * 16) ^ sw));
      bfr[ni][1] = *(const bf16x8*)(base + ((64 + lk * 16) ^ sw));
    }
#pragma unroll
    for (int mi = 0; mi < MFR; mi++) {
      int r = wm * (MFR * 16) + mi * 16 + lr;
      const unsigned char* base = buf + r * 128;
      int sw = (r & 7) << 4;
      bf16x8 ah = *(const bf16x8*)(base + ((lk * 16) ^ sw));
      bf16x8 al = *(const bf16x8*)(base + ((64 + lk * 16) ^ sw));
#pragma unroll
      for (int ni = 0; ni < 4; ni++) {
        acc[mi][ni] = __builtin_amdgcn_mfma_f32_16x16x32_bf16(ah, bfr[ni][0], acc[mi][ni], 0, 0, 0);
        acc[mi][ni] = __builtin_amdgcn_mfma_f32_16x16x32_bf16(ah, bfr[ni][1], acc[mi][ni], 0, 0, 0);
        acc[mi][ni] = __builtin_amdgcn_mfma_f32_16x16x32_bf16(al, bfr[ni][0], acc[mi][ni], 0, 0, 0);
      }
    }
    __syncthreads();
  }

  const int rowb = row0 + wm * (MFR * 16) + ((lane >> 4) * 4);
  if (MODE == 1) {
#pragma unroll
    for (int mi = 0; mi < MFR; mi++)
#pragma unroll
      for (int ni = 0; ni < 4; ni++) {
        int col = blockIdx.y * 128 + wn * 64 + ni * 16 + (lane & 15);
        float bb = bq[col];
#pragma unroll
        for (int g = 0; g < 4; g++) {
          int rr = rowb + mi * 16 + g;
          oOut[(size_t)rr * 512 + col] = acc[mi][ni][g] + bb;
        }
      }
    return;
  }
  const int region = blockIdx.y >> 2;                 // 0=Q 1=K 2=V
  const float* bias = (region == 0) ? bq : (region == 1) ? bk : bv;
  const int cm0 = (blockIdx.y & 3) * 128;
#pragma unroll
  for (int mi = 0; mi < MFR; mi++)
#pragma unroll
    for (int ni = 0; ni < 4; ni++) {
      int c = cm0 + wn * 64 + ni * 16 + (lane & 15);
      float bb = bias[c];
      if (region == 2) {
#pragma unroll
        for (int g = 0; g < 4; g++) {
          int rr = rowb + mi * 16 + g;
          int b = rr >> 11, s = rr & 2047;
          oVT[((size_t)b * 512 + c) * SP + PAD + s] = (bf16)(acc[mi][ni][g] + bb);
        }
      } else {
        int j = c >> 1, par = c & 1;
#pragma unroll
        for (int g = 0; g < 4; g++) {
          int rr = rowb + mi * 16 + g;
          int s = rr & 2047;
          float v = acc[mi][ni][g] + bb;
          float p = __shfl_xor(v, 1);
          float es = sinT[s * 256 + j], ec = cosT[s * 256 + j];
          float res = par ? (p * es + v * ec) : (v * ec - p * es);
          int oc = par ? (j + 256) : j;
          if (region == 0) oQ[(size_t)rr * 512 + oc] = (bf16)res;
          else { int b = rr >> 11; oK[((size_t)b * SP + PAD + s) * 512 + oc] = (bf16)res; }
        }
      }
    }
}

// ---------------- banded MFMA attention (n-split grid) ------------------
// grid (128, 2): block = 32 queries x 256 output h-cols (y half).
// Phase 1: S = Q K^T (8 LDS-staged K-chunks of 64, gload_lds)
// Phase 2: banded softmax (valid iff i <= j <= i+127), P -> bf16 LDS
// Phase 3: out = P V via pVT (h-major), 2 chunks of 128 h-cols
__global__ __launch_bounds__(256) void attn_mfma_k(
    const bf16* __restrict__ rQb, const bf16* __restrict__ pKb,
    const bf16* __restrict__ pVT, bf16* __restrict__ ahi, bf16* __restrict__ alo)
{
  __shared__ __align__(16) unsigned char smem[53760];
  const int tid = threadIdx.x, lane = tid & 63, w = tid >> 6;
  const int q0g = blockIdx.x * TQ;
  const int nbase = blockIdx.y * 256;
  const int b = q0g >> 11, s0 = q0g & 2047;
  const int lr = lane & 15, lk = lane >> 4;
  const int OFF_K = 4096, OFF_P = 43008;

  // ---- phase 1: scores
  f32x4 sacc[5] = {};
  const int tm = w >> 1, tnb = (w & 1) * 5;
  for (int k0 = 0; k0 < 512; k0 += 64) {
    __syncthreads();
    {
      int r = tid >> 3, p = tid & 7, l = p ^ (r & 7);
      GLDS16(rQb + (size_t)(q0g + r) * 512 + k0 + l * 8, smem + (w * 64) * 16);
    }
#pragma unroll
    for (int i = 0; i < 5; i++) {
      int c = tid + i * 256;
      int r = c >> 3, p = c & 7, l = p ^ (r & 7);
      GLDS16(pKb + ((size_t)b * SP + s0 + r) * 512 + k0 + l * 8,
             smem + OFF_K + (i * 256 + w * 64) * 16);
    }
    __syncthreads();
#pragma unroll
    for (int kk = 0; kk < 2; kk++) {
      int arow = tm * 16 + lr;
      bf16x8 a = *(const bf16x8*)(smem + arow * 128 + (((kk * 64 + lk * 16) ^ ((arow & 7) << 4))));
#pragma unroll
      for (int i = 0; i < 5; i++) {
        int brow = (tnb + i) * 16 + lr;
        bf16x8 bb = *(const bf16x8*)(smem + OFF_K + brow * 128 + (((kk * 64 + lk * 16) ^ ((brow & 7) << 4))));
        sacc[i] = __builtin_amdgcn_mfma_f32_16x16x32_bf16(a, bb, sacc[i], 0, 0, 0);
      }
    }
  }
  __syncthreads();
  {   // write scores f32 [32][164]
    float* sc = (float*)smem;
#pragma unroll
    for (int i = 0; i < 5; i++) {
      int col = (tnb + i) * 16 + lr;
#pragma unroll
      for (int g = 0; g < 4; g++) {
        int row = tm * 16 + lk * 4 + g;
        sc[row * 164 + col] = sacc[i][g] * SCALE;
      }
    }
  }
  __syncthreads();
  // ---- phase 2: banded softmax, 8 threads per row
  {
    float* sc = (float*)smem;
    bf16* P = (bf16*)(smem + OFF_P);
    int row = tid >> 3, j0 = tid & 7;
    float vals[20];
    float mx = -1e30f;
#pragma unroll
    for (int i = 0; i < 20; i++) {
      int j = j0 + i * 8;
      bool valid = (j >= row) && (j <= row + 127);
      float v = valid ? sc[row * 164 + j] : -1e30f;
      vals[i] = v;
      mx = fmaxf(mx, v);
    }
#pragma unroll
    for (int off = 1; off < 8; off <<= 1) mx = fmaxf(mx, __shfl_xor(mx, off));
    float sum = 0.f;
#pragma unroll
    for (int i = 0; i < 20; i++) {
      float e = (vals[i] > -1e29f) ? __expf(vals[i] - mx) : 0.f;
      vals[i] = e; sum += e;
    }
#pragma unroll
    for (int off = 1; off < 8; off <<= 1) sum += __shfl_xor(sum, off);
    float inv = 1.f / sum;
#pragma unroll
    for (int i = 0; i < 20; i++) {
      int j = j0 + i * 8;
      P[row * 168 + j] = (bf16)(vals[i] * inv);   // row stride 336B
    }
  }
  // ---- phase 3: out = P @ V (this block's 256-col half)
  const bf16* pVTb = pVT + (size_t)b * 512 * SP;
  const int utm = w >> 1, utnb = (w & 1) * 4;
  for (int n0 = nbase; n0 < nbase + 256; n0 += 128) {
    __syncthreads();
    {   // stage V chunk: 128 h-rows x 160 keys, LDS row stride 336B
      int r = tid >> 1, half = tid & 1;
      const bf16* src = pVTb + (size_t)(n0 + r) * SP + s0;
#pragma unroll
      for (int i = 0; i < 10; i++) {
        int slot = half * 10 + i;
        float4 v = *(const float4*)(src + slot * 8);
        *(float4*)(smem + r * 336 + slot * 16) = v;
      }
    }
    __syncthreads();
    f32x4 oacc[4] = {};
#pragma unroll
    for (int tk = 0; tk < 5; tk++) {
      int arow = utm * 16 + lr;
      bf16x8 a = *(const bf16x8*)(smem + OFF_P + arow * 336 + tk * 64 + lk * 16);
#pragma unroll
      for (int i = 0; i < 4; i++) {
        int brow = (utnb + i) * 16 + lr;
        bf16x8 bb = *(const bf16x8*)(smem + brow * 336 + tk * 64 + lk * 16);
        oacc[i] = __builtin_amdgcn_mfma_f32_16x16x32_bf16(a, bb, oacc[i], 0, 0, 0);
      }
    }
#pragma unroll
    for (int i = 0; i < 4; i++) {
      int col = n0 + (utnb + i) * 16 + lr;
#pragma unroll
      for (int g = 0; g < 4; g++) {
        int row = utm * 16 + lk * 4 + g;
        float v = oacc[i][g];
        bf16 h = (bf16)v;
        size_t idx = (size_t)(q0g + row) * 512 + col;
        ahi[idx] = h;
        alo[idx] = (bf16)(v - (float)h);
      }
    }
  }
}

// ---------------- launch -------------------------------------------------
extern "C" void kernel_launch(void* const* d_in, const int* in_sizes, int n_in,
                              void* d_out, int out_size, void* d_ws, size_t ws_size,
                              hipStream_t stream) {
  const float* x  = (const float*)d_in[0];
  const float* Wq = (const float*)d_in[1];
  const float* bq = (const float*)d_in[2];
  const float* Wk = (const float*)d_in[3];
  const float* bk = (const float*)d_in[4];
  const float* Wv = (const float*)d_in[5];
  const float* bv = (const float*)d_in[6];
  const float* Wo = (const float*)d_in[7];
  const float* bo = (const float*)d_in[8];
  float* out = (float*)d_out;

  const size_t NQ = (size_t)B_SZ * S_LEN * H_DIM;  // 2,097,152
  const size_t NP = (size_t)B_SZ * SP * H_DIM;     // 2,228,224
  double* dfreq = (double*)d_ws;                   // 512 f64
  float* sinT = (float*)(dfreq + 512);             // 524288 f32
  float* cosT = sinT + (size_t)S_LEN * 256;        // 524288 f32
  bf16* xhi = (bf16*)(cosT + (size_t)S_LEN * 256); // NQ
  bf16* xlo = xhi + NQ;                            // NQ
  bf16* whi = xlo + NQ;                            // 1M
  bf16* wlo = whi + 2048 * 512;                    // 1M
  bf16* rQb = wlo + 2048 * 512;                    // NQ
  bf16* pKb = rQb + NQ;                            // NP
  bf16* pVT = pKb + NP;                            // NP
  bf16* ahi = pVT + NP;                            // NQ
  bf16* alo = ahi + NQ;                            // NQ

  rope_freq_k<<<1, 512, 0, stream>>>(dfreq);
  rope_tables_k<<<(S_LEN * 128 + 255) / 256, 256, 0, stream>>>(dfreq, sinT, cosT);
  pad_zero_k<<<128, 256, 0, stream>>>(pKb, pVT);
  conv_split_k<<<(int)(NQ / 4 / 256), 256, 0, stream>>>(x, xhi, xlo, (int)NQ);
  conv_w_k<<<2048 * 512 / 4 / 256, 256, 0, stream>>>(Wq, Wk, Wv, Wo, whi, wlo);

  gemm_k<4, 0><<<dim3(32, 12), 256, 0, stream>>>(xhi, xlo, whi, wlo,
      bq, bk, bv, sinT, cosT, rQb, pKb, pVT, nullptr);

  attn_mfma_k<<<dim3(B_SZ * S_LEN / TQ, 2), 256, 0, stream>>>(rQb, pKb, pVT, ahi, alo);

  gemm_k<2, 1><<<dim3(64, 4), 256, 0, stream>>>(ahi, alo, whi, wlo,
      bo, nullptr, nullptr, sinT, cosT, nullptr, nullptr, nullptr, out);
}

// Round 5
// 59.731 us; speedup vs baseline: 6.4525x; 1.2910x over previous
//
#include <hip/hip_runtime.h>
#include <math.h>

#define S_LEN 2048
#define B_SZ  2
#define H_DIM 512
#define WIN   128
#define PAD   64
#define SP    (S_LEN + WIN)   /* 2176 padded seq length */
#define SCALE 0.044194173824159216f  /* 1/sqrt(512) */
#define TQ    32

typedef __bf16 bf16;
typedef __attribute__((ext_vector_type(8))) __bf16 bf16x8;
typedef __attribute__((ext_vector_type(4))) __bf16 bf16x4;
typedef __attribute__((ext_vector_type(4))) float f32x4;

#define GLDS16(g, l) __builtin_amdgcn_global_load_lds( \
    (const __attribute__((address_space(1))) void*)(g), \
    (__attribute__((address_space(3))) void*)(l), 16, 0, 0)

// ---------------- fused prep: x->bf16 | W->hi/lo | pads | rope tables ----
// R0: [0,262144)       x -> xb (8 elems/thread)
// R1: [262144,524288)  Wq|Wk|Wv|Wo -> whi/wlo (4 elems/thread)
// R2: [524288,557056)  zero pads of pKb (row-pad) and pVT (col-pad)
// R3: [557056,819200)  rope tables via exp2f/sinf (f32)
__global__ __launch_bounds__(256) void prep_k(
    const float* __restrict__ x,
    const float* __restrict__ Wq, const float* __restrict__ Wk,
    const float* __restrict__ Wv, const float* __restrict__ Wo,
    bf16* __restrict__ xb, bf16* __restrict__ whi, bf16* __restrict__ wlo,
    bf16* __restrict__ pKb, bf16* __restrict__ pVT,
    float* __restrict__ sinT, float* __restrict__ cosT)
{
  int i = blockIdx.x * 256 + threadIdx.x;
  if (i < 262144) {                     // R0: x -> bf16
    int e = i * 8;
    float4 v0 = *(const float4*)(x + e);
    float4 v1 = *(const float4*)(x + e + 4);
    bf16x8 o = {(bf16)v0.x, (bf16)v0.y, (bf16)v0.z, (bf16)v0.w,
                (bf16)v1.x, (bf16)v1.y, (bf16)v1.z, (bf16)v1.w};
    *(bf16x8*)(xb + e) = o;
  } else if (i < 524288) {              // R1: weights hi/lo
    int idx = (i - 262144) * 4;
    int m = idx >> 18;
    const float* src = (m == 0) ? Wq : (m == 1) ? Wk : (m == 2) ? Wv : Wo;
    float4 v = *(const float4*)(src + (idx & 262143));
    bf16 h0 = (bf16)v.x, h1 = (bf16)v.y, h2 = (bf16)v.z, h3 = (bf16)v.w;
    bf16x4 hv = {h0, h1, h2, h3};
    bf16x4 lv = {(bf16)(v.x - (float)h0), (bf16)(v.y - (float)h1),
                 (bf16)(v.z - (float)h2), (bf16)(v.w - (float)h3)};
    *(bf16x4*)(whi + idx) = hv;
    *(bf16x4*)(wlo + idx) = lv;
  } else if (i < 557056) {              // R2: pads
    int idx = i - 524288;
    float4 z = {0.f, 0.f, 0.f, 0.f};
    if (idx < 16384) {        // pKb: 2b x 128 pad-rows x 512 cols
      int b = idx >> 13, r = (idx & 8191) >> 6, c = idx & 63;
      int row = (r < 64) ? r : (S_LEN + r);
      *(float4*)(pKb + ((size_t)b * SP + row) * 512 + c * 8) = z;
    } else {                  // pVT: 2b x 512 rows x 128 pad-cols
      int j = idx - 16384;
      int b = j >> 13, h = (j & 8191) >> 4, v = j & 15;
      int col = (v < 8) ? v * 8 : (S_LEN + PAD + (v - 8) * 8);
      *(float4*)(pVT + ((size_t)b * 512 + h) * SP + col) = z;
    }
  } else {                              // R3: rope tables
    int idx = i - 557056;               // [0, 262144) = s*128 + jj
    int s = idx >> 7, jj = idx & 127;
    // inv_freq_i = 10000^(-i/256) = exp2(-i*log2(1e4)/256)
    float fqA = exp2f(-(float)jj * 0.10381025296523f);          // i = 2jj
    float fqB = exp2f(-(float)(2 * jj + 1) * 0.05190512648262f); // i = 2jj+1
    float aA = (float)s * fqA;
    float aB = (float)s * fqB;
    sinT[s * 256 + jj]       = sinf(aA);
    sinT[s * 256 + jj + 128] = cosf(aA);
    cosT[s * 256 + jj]       = sinf(aB);
    cosT[s * 256 + jj + 128] = cosf(aB);
  }
}

// ---------------- 2-pass split-bf16 MFMA GEMM ---------------------------
// C = A(bf16) @ [Whi + Wlo](f32-ish)^T : acc += Ah*Bh + Ah*Bl
// MODE 0: fused QKV -> bf16 rQ (rope), bf16 pK (rope+pad), bf16 pVT (T+pad)
// MODE 1: O-proj -> f32 out (bias in bq slot)
// A LDS rows 64B (4x16B slots, XOR (r&3)); B rows 128B [hi|lo] (XOR (r&7)).
// gload_lds linear dest + inverse-swizzled global source (rule 21).
template<int MFR, int MODE>
__global__ __launch_bounds__(256) void gemm_k(
    const bf16* __restrict__ Ab,
    const bf16* __restrict__ Whi, const bf16* __restrict__ Wlo,
    const float* __restrict__ bq, const float* __restrict__ bk,
    const float* __restrict__ bv,
    const float* __restrict__ sinT, const float* __restrict__ cosT,
    bf16* __restrict__ oQ, bf16* __restrict__ oK, bf16* __restrict__ oVT,
    float* __restrict__ oOut)
{
  constexpr int BM = MFR * 32;
  constexpr int ABYTES = BM * 64;
  constexpr int BUFB = ABYTES + 128 * 128;
  __shared__ __align__(16) unsigned char smem[2 * BUFB];
  const int tid = threadIdx.x;
  const int lane = tid & 63, wid = tid >> 6;
  const int wm = wid >> 1, wn = wid & 1;
  const int row0 = blockIdx.x * BM;
  const int wrow0 = (MODE == 0 ? 0 : 1536) + blockIdx.y * 128;
  const int lr = lane & 15, lk = lane >> 4;

  f32x4 acc[MFR][4] = {};

  auto stage = [&](int k0, int bufsel) {
    unsigned char* buf = smem + bufsel * BUFB;
#pragma unroll
    for (int i = 0; i < MFR / 2; i++) {     // A: BM rows x 4 slots (hi only)
      int c = tid + i * 256;
      int r = c >> 2, p = c & 3, l = p ^ (r & 3);
      GLDS16(Ab + (size_t)(row0 + r) * 512 + k0 + l * 8, buf + c * 16);
    }
#pragma unroll
    for (int j = 0; j < 4; j++) {           // B: 128 rows x 8 slots [hi|lo]
      int c = tid + j * 256;
      int r = c >> 3, p = c & 7, l = p ^ (r & 7);
      const bf16* src = ((l < 4) ? Whi : Wlo) + (size_t)(wrow0 + r) * 512 + k0 + (l & 3) * 8;
      GLDS16(src, buf + ABYTES + c * 16);
    }
  };

  stage(0, 0);
  __syncthreads();
  for (int t = 0; t < 16; t++) {
    if (t < 15) stage((t + 1) * 32, (t + 1) & 1);
    const unsigned char* buf = smem + (t & 1) * BUFB;
    bf16x8 bfr[4][2];
#pragma unroll
    for (int ni = 0; ni < 4; ni++) {
      int r = wn * 64 + ni * 16 + lr;
      const unsigned char* base = buf + ABYTES + r * 128;
      int sw = (r & 7) << 4;
      bfr[ni][0] = *(const bf16x8*)(base + ((lk * 16) ^ sw));
      bfr[ni][1] = *(const bf16x8*)(base + ((64 + lk * 16) ^ sw));
    }
    bf16x8 ah[MFR];
#pragma unroll
    for (int mi = 0; mi < MFR; mi++) {
      int r = wm * (MFR * 16) + mi * 16 + lr;
      ah[mi] = *(const bf16x8*)(buf + r * 64 + ((lk * 16) ^ ((r & 3) << 4)));
    }
#pragma unroll
    for (int mi = 0; mi < MFR; mi++)
#pragma unroll
      for (int ni = 0; ni < 4; ni++) {
        acc[mi][ni] = __builtin_amdgcn_mfma_f32_16x16x32_bf16(ah[mi], bfr[ni][0], acc[mi][ni], 0, 0, 0);
        acc[mi][ni] = __builtin_amdgcn_mfma_f32_16x16x32_bf16(ah[mi], bfr[ni][1], acc[mi][ni], 0, 0, 0);
      }
    __syncthreads();
  }

  const int rowb = row0 + wm * (MFR * 16) + ((lane >> 4) * 4);
  if (MODE == 1) {
#pragma unroll
    for (int mi = 0; mi < MFR; mi++)
#pragma unroll
      for (int ni = 0; ni < 4; ni++) {
        int col = blockIdx.y * 128 + wn * 64 + ni * 16 + (lane & 15);
        float bb = bq[col];
#pragma unroll
        for (int g = 0; g < 4; g++) {
          int rr = rowb + mi * 16 + g;
          oOut[(size_t)rr * 512 + col] = acc[mi][ni][g] + bb;
        }
      }
    return;
  }
  const int region = blockIdx.y >> 2;                 // 0=Q 1=K 2=V
  const float* bias = (region == 0) ? bq : (region == 1) ? bk : bv;
  const int cm0 = (blockIdx.y & 3) * 128;
#pragma unroll
  for (int mi = 0; mi < MFR; mi++)
#pragma unroll
    for (int ni = 0; ni < 4; ni++) {
      int c = cm0 + wn * 64 + ni * 16 + (lane & 15);
      float bb = bias[c];
      if (region == 2) {
#pragma unroll
        for (int g = 0; g < 4; g++) {
          int rr = rowb + mi * 16 + g;
          int b = rr >> 11, s = rr & 2047;
          oVT[((size_t)b * 512 + c) * SP + PAD + s] = (bf16)(acc[mi][ni][g] + bb);
        }
      } else {
        int j = c >> 1, par = c & 1;
#pragma unroll
        for (int g = 0; g < 4; g++) {
          int rr = rowb + mi * 16 + g;
          int s = rr & 2047;
          float v = acc[mi][ni][g] + bb;
          float p = __shfl_xor(v, 1);
          float es = sinT[s * 256 + j], ec = cosT[s * 256 + j];
          float res = par ? (p * es + v * ec) : (v * ec - p * es);
          int oc = par ? (j + 256) : j;
          if (region == 0) oQ[(size_t)rr * 512 + oc] = (bf16)res;
          else { int b = rr >> 11; oK[((size_t)b * SP + PAD + s) * 512 + oc] = (bf16)res; }
        }
      }
    }
}

// ---------------- banded MFMA attention (n-split grid) ------------------
// grid (128, 2): block = 32 queries x 256 output h-cols (y half).
// Phase 1: S = Q K^T (8 LDS-staged K-chunks of 64, gload_lds)
// Phase 2: banded softmax (valid iff i <= j <= i+127), P -> bf16 LDS
// Phase 3: out = P V via pVT (h-major), 2 chunks of 128 h-cols; out bf16.
__global__ __launch_bounds__(256) void attn_mfma_k(
    const bf16* __restrict__ rQb, const bf16* __restrict__ pKb,
    const bf16* __restrict__ pVT, bf16* __restrict__ ab)
{
  __shared__ __align__(16) unsigned char smem[53760];
  const int tid = threadIdx.x, lane = tid & 63, w = tid >> 6;
  const int q0g = blockIdx.x * TQ;
  const int nbase = blockIdx.y * 256;
  const int b = q0g >> 11, s0 = q0g & 2047;
  const int lr = lane & 15, lk = lane >> 4;
  const int OFF_K = 4096, OFF_P = 43008;

  // ---- phase 1: scores
  f32x4 sacc[5] = {};
  const int tm = w >> 1, tnb = (w & 1) * 5;
  for (int k0 = 0; k0 < 512; k0 += 64) {
    __syncthreads();
    {
      int r = tid >> 3, p = tid & 7, l = p ^ (r & 7);
      GLDS16(rQb + (size_t)(q0g + r) * 512 + k0 + l * 8, smem + (w * 64) * 16);
    }
#pragma unroll
    for (int i = 0; i < 5; i++) {
      int c = tid + i * 256;
      int r = c >> 3, p = c & 7, l = p ^ (r & 7);
      GLDS16(pKb + ((size_t)b * SP + s0 + r) * 512 + k0 + l * 8,
             smem + OFF_K + (i * 256 + w * 64) * 16);
    }
    __syncthreads();
#pragma unroll
    for (int kk = 0; kk < 2; kk++) {
      int arow = tm * 16 + lr;
      bf16x8 a = *(const bf16x8*)(smem + arow * 128 + (((kk * 64 + lk * 16) ^ ((arow & 7) << 4))));
#pragma unroll
      for (int i = 0; i < 5; i++) {
        int brow = (tnb + i) * 16 + lr;
        bf16x8 bb = *(const bf16x8*)(smem + OFF_K + brow * 128 + (((kk * 64 + lk * 16) ^ ((brow & 7) << 4))));
        sacc[i] = __builtin_amdgcn_mfma_f32_16x16x32_bf16(a, bb, sacc[i], 0, 0, 0);
      }
    }
  }
  __syncthreads();
  {   // write scores f32 [32][164]
    float* sc = (float*)smem;
#pragma unroll
    for (int i = 0; i < 5; i++) {
      int col = (tnb + i) * 16 + lr;
#pragma unroll
      for (int g = 0; g < 4; g++) {
        int row = tm * 16 + lk * 4 + g;
        sc[row * 164 + col] = sacc[i][g] * SCALE;
      }
    }
  }
  __syncthreads();
  // ---- phase 2: banded softmax, 8 threads per row
  {
    float* sc = (float*)smem;
    bf16* P = (bf16*)(smem + OFF_P);
    int row = tid >> 3, j0 = tid & 7;
    float vals[20];
    float mx = -1e30f;
#pragma unroll
    for (int i = 0; i < 20; i++) {
      int j = j0 + i * 8;
      bool valid = (j >= row) && (j <= row + 127);
      float v = valid ? sc[row * 164 + j] : -1e30f;
      vals[i] = v;
      mx = fmaxf(mx, v);
    }
#pragma unroll
    for (int off = 1; off < 8; off <<= 1) mx = fmaxf(mx, __shfl_xor(mx, off));
    float sum = 0.f;
#pragma unroll
    for (int i = 0; i < 20; i++) {
      float e = (vals[i] > -1e29f) ? __expf(vals[i] - mx) : 0.f;
      vals[i] = e; sum += e;
    }
#pragma unroll
    for (int off = 1; off < 8; off <<= 1) sum += __shfl_xor(sum, off);
    float inv = 1.f / sum;
#pragma unroll
    for (int i = 0; i < 20; i++) {
      int j = j0 + i * 8;
      P[row * 168 + j] = (bf16)(vals[i] * inv);   // row stride 336B
    }
  }
  // ---- phase 3: out = P @ V (this block's 256-col half)
  const bf16* pVTb = pVT + (size_t)b * 512 * SP;
  const int utm = w >> 1, utnb = (w & 1) * 4;
  for (int n0 = nbase; n0 < nbase + 256; n0 += 128) {
    __syncthreads();
    {   // stage V chunk: 128 h-rows x 160 keys, LDS row stride 336B
      int r = tid >> 1, half = tid & 1;
      const bf16* src = pVTb + (size_t)(n0 + r) * SP + s0;
#pragma unroll
      for (int i = 0; i < 10; i++) {
        int slot = half * 10 + i;
        float4 v = *(const float4*)(src + slot * 8);
        *(float4*)(smem + r * 336 + slot * 16) = v;
      }
    }
    __syncthreads();
    f32x4 oacc[4] = {};
#pragma unroll
    for (int tk = 0; tk < 5; tk++) {
      int arow = utm * 16 + lr;
      bf16x8 a = *(const bf16x8*)(smem + OFF_P + arow * 336 + tk * 64 + lk * 16);
#pragma unroll
      for (int i = 0; i < 4; i++) {
        int brow = (utnb + i) * 16 + lr;
        bf16x8 bb = *(const bf16x8*)(smem + brow * 336 + tk * 64 + lk * 16);
        oacc[i] = __builtin_amdgcn_mfma_f32_16x16x32_bf16(a, bb, oacc[i], 0, 0, 0);
      }
    }
#pragma unroll
    for (int i = 0; i < 4; i++) {
      int col = n0 + (utnb + i) * 16 + lr;
#pragma unroll
      for (int g = 0; g < 4; g++) {
        int row = utm * 16 + lk * 4 + g;
        ab[(size_t)(q0g + row) * 512 + col] = (bf16)oacc[i][g];
      }
    }
  }
}

// ---------------- launch -------------------------------------------------
extern "C" void kernel_launch(void* const* d_in, const int* in_sizes, int n_in,
                              void* d_out, int out_size, void* d_ws, size_t ws_size,
                              hipStream_t stream) {
  const float* x  = (const float*)d_in[0];
  const float* Wq = (const float*)d_in[1];
  const float* bq = (const float*)d_in[2];
  const float* Wk = (const float*)d_in[3];
  const float* bk = (const float*)d_in[4];
  const float* Wv = (const float*)d_in[5];
  const float* bv = (const float*)d_in[6];
  const float* Wo = (const float*)d_in[7];
  const float* bo = (const float*)d_in[8];
  float* out = (float*)d_out;

  const size_t NQ = (size_t)B_SZ * S_LEN * H_DIM;  // 2,097,152
  const size_t NP = (size_t)B_SZ * SP * H_DIM;     // 2,228,224
  float* sinT = (float*)d_ws;                      // 524288 f32
  float* cosT = sinT + (size_t)S_LEN * 256;        // 524288 f32
  bf16* xb  = (bf16*)(cosT + (size_t)S_LEN * 256); // NQ
  bf16* whi = xb + NQ;                             // 1M
  bf16* wlo = whi + 2048 * 512;                    // 1M
  bf16* rQb = wlo + 2048 * 512;                    // NQ
  bf16* pKb = rQb + NQ;                            // NP
  bf16* pVT = pKb + NP;                            // NP
  bf16* ab  = pVT + NP;                            // NQ

  prep_k<<<3200, 256, 0, stream>>>(x, Wq, Wk, Wv, Wo, xb, whi, wlo,
                                   pKb, pVT, sinT, cosT);

  gemm_k<4, 0><<<dim3(32, 12), 256, 0, stream>>>(xb, whi, wlo,
      bq, bk, bv, sinT, cosT, rQb, pKb, pVT, nullptr);

  attn_mfma_k<<<dim3(B_SZ * S_LEN / TQ, 2), 256, 0, stream>>>(rQb, pKb, pVT, ab);

  gemm_k<2, 1><<<dim3(64, 4), 256, 0, stream>>>(ab, whi, wlo,
      bo, nullptr, nullptr, sinT, cosT, nullptr, nullptr, nullptr, out);
}